// Round 3
// baseline (98.454 us; speedup 1.0000x reference)
//
#include <hip/hip_runtime.h>
#include <hip/hip_bf16.h>

#define LL 2048
#define CC 64

typedef __bf16 bf16x8 __attribute__((ext_vector_type(8)));
typedef float f32x4 __attribute__((ext_vector_type(4)));

__global__ void zero_ws_k(float* ws, int n) {
  int i = blockIdx.x * blockDim.x + threadIdx.x;
  if (i < n) ws[i] = 0.f;
}

// native RNE casts -> compiler emits v_cvt(_pk)_bf16_f32 on gfx950
__device__ __forceinline__ bf16x8 mk8(f32x4 lo, f32x4 hi) {
  bf16x8 r;
  r[0] = (__bf16)lo[0]; r[1] = (__bf16)lo[1]; r[2] = (__bf16)lo[2]; r[3] = (__bf16)lo[3];
  r[4] = (__bf16)hi[0]; r[5] = (__bf16)hi[1]; r[6] = (__bf16)hi[2]; r[7] = (__bf16)hi[3];
  return r;
}

__global__ __launch_bounds__(256) void l2disc_main(
    const float* __restrict__ times, const float* __restrict__ path1,
    const float* __restrict__ path2, const float* __restrict__ Amat,
    float* __restrict__ wsacc)
{
  const int lane = threadIdx.x & 63;
  const int wave = threadIdx.x >> 6;
  const int c = lane & 15;      // A-frag row within tile / output channel sub-index
  const int g = lane >> 4;      // k-group / row-quad index in C/D
  const int b = blockIdx.x >> 2;
  const int q = ((blockIdx.x & 3) << 2) | wave;   // span 0..15
  const int p0 = q << 7;                          // first pair index owned
  const int ntile = (q == 15) ? 8 : 9;            // tile 8 = 1-row overlap (c==0 valid)

  // ---- B-operand fragments from A (same k-bijection on A- and B-frags)
  bf16x8 bfr[4][2];
  #pragma unroll
  for (int t = 0; t < 4; ++t) {
    #pragma unroll
    for (int s = 0; s < 2; ++s) {
      const float* ap = Amat + (16 * t + c) * CC + 32 * s + (g << 3);
      f32x4 x0 = *(const f32x4*)ap;
      f32x4 x1 = *(const f32x4*)(ap + 4);
      bfr[t][s] = mk8(x0, x1);
    }
  }

  const float* p1base = path1 + (size_t)b * LL * CC;

  float wacc = 0.f;
  f32x4 prev = {0.f, 0.f, 0.f, 0.f};
  float dm1carry = 0.f;

  // double buffers (named, statically indexed)
  f32x4 p2A[4], p1A[4], p2B[4], p1B[4];
  f32x4 t4A, t4B; float t5A, t5B;

  auto LOADT = [&](int i, f32x4* p2v, f32x4* p1v, f32x4& t4, float& t5) {
    const int r0 = p0 + (i << 4);
    const int row = r0 + c;                 // always in-bounds (max 1935 < 2048)
    const float* pp2 = path2 + (size_t)row * CC + (g << 3);
    p2v[0] = *(const f32x4*)(pp2);      p2v[1] = *(const f32x4*)(pp2 + 4);
    p2v[2] = *(const f32x4*)(pp2 + 32); p2v[3] = *(const f32x4*)(pp2 + 36);
    const float* pp1 = p1base + (size_t)row * CC + (g << 3);
    p1v[0] = *(const f32x4*)(pp1);      p1v[1] = *(const f32x4*)(pp1 + 4);
    p1v[2] = *(const f32x4*)(pp1 + 32); p1v[3] = *(const f32x4*)(pp1 + 36);
    t4 = *(const f32x4*)(times + r0 + (g << 2));
    t5 = times[min(r0 + (g << 2) + 4, LL - 1)];
  };

  auto COMP = [&](int i, const f32x4* p2v, const f32x4* p1v, f32x4 t4, float t5) {
    const bool full = (i < 8);
    bf16x8 af0, af1;
    if (full || c == 0) {
      af0 = mk8(p1v[0] - p2v[0], p1v[1] - p2v[1]);
      af1 = mk8(p1v[2] - p2v[2], p1v[3] - p2v[3]);
    } else {
      bf16x8 z = {};
      af0 = z; af1 = z;
    }

    f32x4 y[4];
    #pragma unroll
    for (int t = 0; t < 4; ++t) { f32x4 zz = {0.f,0.f,0.f,0.f}; y[t] = zz; }
    #pragma unroll
    for (int t = 0; t < 4; ++t)
      y[t] = __builtin_amdgcn_mfma_f32_16x16x32_bf16(af0, bfr[t][0], y[t], 0, 0, 0);
    #pragma unroll
    for (int t = 0; t < 4; ++t)
      y[t] = __builtin_amdgcn_mfma_f32_16x16x32_bf16(af1, bfr[t][1], y[t], 0, 0, 0);

    const float d0 = t4[1] - t4[0], d1 = t4[2] - t4[1], d2 = t4[3] - t4[2];
    const float d3 = t5 - t4[3];
    const float dm1 = dm1carry;   // times[r0] - times[r0-1], from prev tile's g=3 d3

    if (full) {
      // in-lane adjacent pairs: rows (4g+r, 4g+r+1), r=0..2
      float s0 = 0.f, s1 = 0.f, s2 = 0.f;
      #pragma unroll
      for (int t = 0; t < 4; ++t) {
        float a, bb;
        a = y[t][0]; bb = y[t][1]; s0 += a*a + a*bb + bb*bb;
        a = y[t][1]; bb = y[t][2]; s1 += a*a + a*bb + bb*bb;
        a = y[t][2]; bb = y[t][3]; s2 += a*a + a*bb + bb*bb;
      }
      wacc += d0 * s0 + d1 * s1 + d2 * s2;
      // cross-reg-group pair: rows (4g+3, 4g+4) via lane+16
      float nb0 = __shfl_down(y[0][0], 16);
      float nb1 = __shfl_down(y[1][0], 16);
      float nb2 = __shfl_down(y[2][0], 16);
      float nb3 = __shfl_down(y[3][0], 16);
      if (g < 3) {
        float a, s = 0.f;
        a = y[0][3]; s += a*a + a*nb0 + nb0*nb0;
        a = y[1][3]; s += a*a + a*nb1 + nb1*nb1;
        a = y[2][3]; s += a*a + a*nb2 + nb2*nb2;
        a = y[3][3]; s += a*a + a*nb3 + nb3*nb3;
        wacc += d3 * s;
      }
    }
    // cross-tile pair: rows (r0-1, r0) — only g==0 lanes hold row r0 in y[t][0]
    if (i > 0 && g == 0) {
      float s = 0.f;
      #pragma unroll
      for (int t = 0; t < 4; ++t) {
        float a = prev[t], bb = y[t][0];
        s += a*a + a*bb + bb*bb;
      }
      wacc += dm1 * s;
    }
    if (full) {
      #pragma unroll
      for (int t = 0; t < 4; ++t) prev[t] = __shfl(y[t][3], 48 + c);
    }
    dm1carry = __shfl(d3, 48);    // g=3's d3 = times[r0+16]-times[r0+15]
  };

  // ---- software-pipelined main loop (prefetch depth 1, static buffers)
  LOADT(0, p2A, p1A, t4A, t5A);
  int i = 0;
  while (true) {
    if (i + 1 < ntile) LOADT(i + 1, p2B, p1B, t4B, t5B);
    COMP(i, p2A, p1A, t4A, t5A);
    if (i + 1 >= ntile) break;
    if (i + 2 < ntile) LOADT(i + 2, p2A, p1A, t4A, t5A);
    COMP(i + 1, p2B, p1B, t4B, t5B);
    i += 2;
    if (i >= ntile) break;
  }

  // ---- wave reduce + one atomic per wave
  #pragma unroll
  for (int off = 32; off > 0; off >>= 1) wacc += __shfl_down(wacc, off);
  if (lane == 0) atomicAdd(wsacc + b, wacc);
}

__global__ void fin_k(const float* __restrict__ ws, float* __restrict__ out, int n) {
  int i = blockIdx.x * blockDim.x + threadIdx.x;
  if (i < n) out[i] = sqrtf(ws[i] * (1.0f / 3.0f));
}

extern "C" void kernel_launch(void* const* d_in, const int* in_sizes, int n_in,
                              void* d_out, int out_size, void* d_ws, size_t ws_size,
                              hipStream_t stream) {
  const float* times = (const float*)d_in[0];
  const float* path1 = (const float*)d_in[1];
  const float* path2 = (const float*)d_in[2];
  const float* Amat  = (const float*)d_in[3];
  float* out = (float*)d_out;
  float* ws  = (float*)d_ws;
  const int B = in_sizes[1] / (LL * CC);  // 512

  hipLaunchKernelGGL(zero_ws_k, dim3((B + 255) / 256), dim3(256), 0, stream, ws, B);
  hipLaunchKernelGGL(l2disc_main, dim3(B * 4), dim3(256), 0, stream,
                     times, path1, path2, Amat, ws);
  hipLaunchKernelGGL(fin_k, dim3((B + 255) / 256), dim3(256), 0, stream, ws, out, B);
}

// Round 4
// 74.786 us; speedup vs baseline: 1.3165x; 1.3165x over previous
//
#include <hip/hip_runtime.h>
#include <hip/hip_bf16.h>

#define LL 2048
#define CC 64

typedef __bf16 bf16x8 __attribute__((ext_vector_type(8)));
typedef float f32x4 __attribute__((ext_vector_type(4)));

__global__ void zero_ws_k(float* ws, int n) {
  int i = blockIdx.x * blockDim.x + threadIdx.x;
  if (i < n) ws[i] = 0.f;
}

// native RNE casts -> v_cvt_pk_bf16_f32 on gfx950
__device__ __forceinline__ bf16x8 mk8(f32x4 lo, f32x4 hi) {
  bf16x8 r;
  r[0] = (__bf16)lo[0]; r[1] = (__bf16)lo[1]; r[2] = (__bf16)lo[2]; r[3] = (__bf16)lo[3];
  r[4] = (__bf16)hi[0]; r[5] = (__bf16)hi[1]; r[6] = (__bf16)hi[2]; r[7] = (__bf16)hi[3];
  return r;
}

// async global->LDS, 16B per lane; LDS dest = uniform base + lane*16
__device__ __forceinline__ void gl16(const float* g, float* l) {
  __builtin_amdgcn_global_load_lds(
      (const __attribute__((address_space(1))) unsigned int*)g,
      (__attribute__((address_space(3))) unsigned int*)l, 16, 0, 0);
}

__global__ __launch_bounds__(256) void l2disc_main(
    const float* __restrict__ times, const float* __restrict__ path1,
    const float* __restrict__ path2, const float* __restrict__ Amat,
    float* __restrict__ wsacc)
{
  // 4 waves * 2 parities * 2 arrays * 1024 floats = 64 KB
  __shared__ float lds[16384];

  const int lane = threadIdx.x & 63;
  const int wave = threadIdx.x >> 6;
  const int c = lane & 15;      // A-frag row within tile / output channel sub-index
  const int g = lane >> 4;      // k-group / row-quad index in C/D
  const int b = blockIdx.x >> 2;
  const int q = ((blockIdx.x & 3) << 2) | wave;   // span 0..15
  const int p0 = q << 7;
  const int ntile = (q == 15) ? 8 : 9;            // tile 8 = 1-row overlap

  // ---- B-operand fragments from A (same k-bijection on A- and B-frags)
  bf16x8 bfr[4][2];
  #pragma unroll
  for (int t = 0; t < 4; ++t) {
    #pragma unroll
    for (int s = 0; s < 2; ++s) {
      const float* ap = Amat + (16 * t + c) * CC + 32 * s + (g << 3);
      f32x4 x0 = *(const f32x4*)ap;
      f32x4 x1 = *(const f32x4*)(ap + 4);
      bfr[t][s] = mk8(x0, x1);
    }
  }

  // ---- per-lane swizzled STAGE source offsets (float units)
  // chunk lane l -> dest floats [4l,4l+4) of a 1KB block; row = 4j + (l>>4)
  // source f = f_display ^ ((row&7)<<2)
  const int lr = lane >> 4, lcf = (lane & 15) << 2;
  const int soffE = lr * 64 + (lcf ^ (lr << 2));         // j even: row&7 = lr
  const int soffO = lr * 64 + (lcf ^ ((lr + 4) << 2));   // j odd : row&7 = lr+4
  // ---- per-lane swizzled READ offsets (float units) within a 1024-float tile
  const int swz = (c & 7) << 2;
  const int rf0 = c * 64 + ((g << 3) ^ swz);
  const int rf1 = c * 64 + (((g << 3) | 4) ^ swz);

  float* wl = lds + wave * 4096;
  const float* p1base = path1 + (size_t)b * LL * CC;

  float wacc = 0.f;
  f32x4 prev = {0.f, 0.f, 0.f, 0.f};
  float dm1carry = 0.f;

  auto STAGE = [&](int i, int par, f32x4& t4, float& t5) {
    const int r0 = p0 + (i << 4);
    const float* s1 = p1base + (size_t)r0 * CC;
    const float* s2 = path2 + (size_t)r0 * CC;
    float* d1 = wl + par * 2048;
    float* d2 = d1 + 1024;
    #pragma unroll
    for (int j = 0; j < 4; ++j) {
      const int so = j * 256 + ((j & 1) ? soffO : soffE);
      gl16(s1 + so, d1 + j * 256);
      gl16(s2 + so, d2 + j * 256);
    }
    t4 = *(const f32x4*)(times + r0 + (g << 2));
    t5 = times[min(r0 + (g << 2) + 4, LL - 1)];
  };

  auto COMP = [&](int i, int par, f32x4 t4, float t5) {
    const bool full = (i < 8);
    const float* u1 = wl + par * 2048;
    const float* u2 = u1 + 1024;

    f32x4 a0 = *(const f32x4*)(u1 + rf0);
    f32x4 a1 = *(const f32x4*)(u1 + rf1);
    f32x4 a2 = *(const f32x4*)(u1 + rf0 + 32);
    f32x4 a3 = *(const f32x4*)(u1 + rf1 + 32);
    f32x4 b0 = *(const f32x4*)(u2 + rf0);
    f32x4 b1 = *(const f32x4*)(u2 + rf1);
    f32x4 b2 = *(const f32x4*)(u2 + rf0 + 32);
    f32x4 b3 = *(const f32x4*)(u2 + rf1 + 32);

    bf16x8 af0 = mk8(a0 - b0, a1 - b1);
    bf16x8 af1 = mk8(a2 - b2, a3 - b3);

    f32x4 y[4];
    #pragma unroll
    for (int t = 0; t < 4; ++t) { f32x4 zz = {0.f,0.f,0.f,0.f}; y[t] = zz; }
    #pragma unroll
    for (int t = 0; t < 4; ++t)
      y[t] = __builtin_amdgcn_mfma_f32_16x16x32_bf16(af0, bfr[t][0], y[t], 0, 0, 0);
    #pragma unroll
    for (int t = 0; t < 4; ++t)
      y[t] = __builtin_amdgcn_mfma_f32_16x16x32_bf16(af1, bfr[t][1], y[t], 0, 0, 0);

    const float d0 = t4[1] - t4[0], d1 = t4[2] - t4[1], d2 = t4[3] - t4[2];
    const float d3 = t5 - t4[3];
    const float dm1 = dm1carry;

    if (full) {
      float s0 = 0.f, s1 = 0.f, s2 = 0.f;
      #pragma unroll
      for (int t = 0; t < 4; ++t) {
        float a, bb;
        a = y[t][0]; bb = y[t][1]; s0 += a*a + a*bb + bb*bb;
        a = y[t][1]; bb = y[t][2]; s1 += a*a + a*bb + bb*bb;
        a = y[t][2]; bb = y[t][3]; s2 += a*a + a*bb + bb*bb;
      }
      wacc += d0 * s0 + d1 * s1 + d2 * s2;
      float nb0 = __shfl_down(y[0][0], 16);
      float nb1 = __shfl_down(y[1][0], 16);
      float nb2 = __shfl_down(y[2][0], 16);
      float nb3 = __shfl_down(y[3][0], 16);
      if (g < 3) {
        float a, s = 0.f;
        a = y[0][3]; s += a*a + a*nb0 + nb0*nb0;
        a = y[1][3]; s += a*a + a*nb1 + nb1*nb1;
        a = y[2][3]; s += a*a + a*nb2 + nb2*nb2;
        a = y[3][3]; s += a*a + a*nb3 + nb3*nb3;
        wacc += d3 * s;
      }
    }
    if (i > 0 && g == 0) {
      float s = 0.f;
      #pragma unroll
      for (int t = 0; t < 4; ++t) {
        float a = prev[t], bb = y[t][0];
        s += a*a + a*bb + bb*bb;
      }
      wacc += dm1 * s;
    }
    if (full) {
      #pragma unroll
      for (int t = 0; t < 4; ++t) prev[t] = __shfl(y[t][3], 48 + c);
    }
    dm1carry = __shfl(d3, 48);
  };

  // ---- pipelined loop: STAGE(i+1) in flight while COMP(i) runs; counted vmcnt
  f32x4 t4A, t4B; float t5A = 0.f, t5B = 0.f;
  STAGE(0, 0, t4A, t5A);
  int i = 0;
  while (true) {
    bool more = (i + 1 < ntile);
    if (more) STAGE(i + 1, 1, t4B, t5B);
    __builtin_amdgcn_sched_barrier(0);
    if (more) asm volatile("s_waitcnt vmcnt(10)" ::: "memory");
    else      asm volatile("s_waitcnt vmcnt(0)"  ::: "memory");
    __builtin_amdgcn_sched_barrier(0);
    COMP(i, 0, t4A, t5A);
    ++i; if (i >= ntile) break;

    more = (i + 1 < ntile);
    if (more) STAGE(i + 1, 0, t4A, t5A);
    __builtin_amdgcn_sched_barrier(0);
    if (more) asm volatile("s_waitcnt vmcnt(10)" ::: "memory");
    else      asm volatile("s_waitcnt vmcnt(0)"  ::: "memory");
    __builtin_amdgcn_sched_barrier(0);
    COMP(i, 1, t4B, t5B);
    ++i; if (i >= ntile) break;
  }

  // ---- wave reduce + one atomic per wave
  #pragma unroll
  for (int off = 32; off > 0; off >>= 1) wacc += __shfl_down(wacc, off);
  if (lane == 0) atomicAdd(wsacc + b, wacc);
}

__global__ void fin_k(const float* __restrict__ ws, float* __restrict__ out, int n) {
  int i = blockIdx.x * blockDim.x + threadIdx.x;
  if (i < n) out[i] = sqrtf(ws[i] * (1.0f / 3.0f));
}

extern "C" void kernel_launch(void* const* d_in, const int* in_sizes, int n_in,
                              void* d_out, int out_size, void* d_ws, size_t ws_size,
                              hipStream_t stream) {
  const float* times = (const float*)d_in[0];
  const float* path1 = (const float*)d_in[1];
  const float* path2 = (const float*)d_in[2];
  const float* Amat  = (const float*)d_in[3];
  float* out = (float*)d_out;
  float* ws  = (float*)d_ws;
  const int B = in_sizes[1] / (LL * CC);  // 512

  hipLaunchKernelGGL(zero_ws_k, dim3((B + 255) / 256), dim3(256), 0, stream, ws, B);
  hipLaunchKernelGGL(l2disc_main, dim3(B * 4), dim3(256), 0, stream,
                     times, path1, path2, Amat, ws);
  hipLaunchKernelGGL(fin_k, dim3((B + 255) / 256), dim3(256), 0, stream, ws, out, B);
}